// Round 5
// baseline (2149.044 us; speedup 1.0000x reference)
//
#include <hip/hip_runtime.h>

// ---------------------------------------------------------------------------
// SimpleGRU on MI355X (gfx950). Round 10b: flag-released XCD-local exchange.
//   Round-9 (PASS, 2.13ms total; rec 3.88us/step): counter-released L2
//     exchange worked, but the release is 32 same-line atomic RMWs at the
//     fabric -> ~1-3us serialization chain; the consumer waits for the LAST
//     increment. That chain is the remaining bottleneck.
//   Now: 32 independent monotonic flags per group. Producer g: 16 sc0 data
//   stores -> vmcnt(0) (data complete in own XCD L2) -> ONE sc0 sc1 store
//   flag[grp][g]=t+1 (no RMW, no serialization) -> truth stores. Consumer:
//   lanes 0..31 poll flag[grp][l] (sc0 sc1, 2 lines/wave, load-only) until
//   __all(flag>=t), then one-shot sc0 data read from the shared XCD L2.
//   Monotonic flags: no reset, no replay staleness (system scope only).
//   Safety (all proven): sentinel check on one-shot read -> truth sentinel
//   poll; sticky downgrade to round-6 semantics; non-32/XCD dispatch ->
//   literal round-6 fallback; sleep escalation damps poll storms.
//   (10b: s_sleep takes a literal -> branch to constant-arg calls.)
// ws: xg bf16 [512][1536][64] (100,663,296 B) | truth [depth][64][512] f16 |
//     fast [8][depth][8][512] f16 | prog int[384] | regs | flag int[8][32]
// ---------------------------------------------------------------------------

typedef unsigned short ushort_t;
typedef short short8      __attribute__((ext_vector_type(8)));
typedef float floatx4     __attribute__((ext_vector_type(4)));
typedef unsigned int uintx4 __attribute__((ext_vector_type(4)));
typedef unsigned short ushort4v __attribute__((ext_vector_type(4)));
typedef _Float16 half8    __attribute__((ext_vector_type(8)));

#define SEQL 512
#define BATCH 64
#define EMBD 256
#define HID 512
#define G3 1536
#define NOUT 5
#define NGRP 8                     // one group per XCD (fast mode)
#define GRPB 8                     // batches per group (fast mode)
#define GSLOT 8192                 // fast ring slot: 8 x 512 x 2B
#define TSLOT 65536                // truth ring slot: 64 x 512 x 2B
#define RING2 131072               // truth + fast bytes per depth unit
#define XG_BYTES 100663296
#define PROGN 512                  // legacy prog area (includes regs at 384)
#define FLAGN 256                  // flag[8][32]
#define ZERON (PROGN + FLAGN)      // ints zeroed by init
#define BAD_LIMIT 8

__device__ __forceinline__ float bf2f(ushort_t v){
  union { unsigned u; float f; } x; x.u = ((unsigned)v) << 16; return x.f;
}
__device__ __forceinline__ ushort_t f2bf(float f){
  unsigned u = __float_as_uint(f);
  return (ushort_t)((u + 0x7FFFu + ((u >> 16) & 1u)) >> 16);
}
__device__ __forceinline__ float sigm(float x){
  x = fminf(fmaxf(x, -20.f), 20.f);
  return 1.f / (1.f + __expf(-x));
}
__device__ __forceinline__ float tanh_c(float x){
  x = fminf(fmaxf(x, -10.f), 10.f);
  float e = __expf(2.f * x);
  return (e - 1.f) / (e + 1.f);
}
__device__ __forceinline__ bool has_sent(half8 v){
  union { half8 h; unsigned u[4]; } x; x.h = v;
  bool b = false;
  #pragma unroll
  for (int i = 0; i < 4; ++i){
    b |= ((x.u[i] & 0xFFFFu) == 0xFFFFu);
    b |= ((x.u[i] >> 16) == 0xFFFFu);
  }
  return b;
}

// --- K0: sentinel-fill both rings at SYSTEM scope; zero prog+flags. ---
__global__ __launch_bounds__(256) void gru_init(char* __restrict__ rings,
                                                int* __restrict__ prog){
  size_t i = ((size_t)blockIdx.x * 256 + threadIdx.x) * 16;
  uintx4 s = {0xFFFFFFFFu, 0xFFFFFFFFu, 0xFFFFFFFFu, 0xFFFFFFFFu};
  const char* p = rings + i;
  asm volatile("global_store_dwordx4 %0, %1, off sc0 sc1" :: "v"(p), "v"(s) : "memory");
  if (blockIdx.x == 0){
    int z = 0;
    for (int k = threadIdx.x; k < ZERON; k += 256){
      asm volatile("global_store_dword %0, %1, off sc0 sc1"
                   :: "v"(prog + k), "v"(z) : "memory");
    }
  }
}

// --- K1: x_gates = emb[seq] @ w_ih^T + b_ih, bf16, layout [s][1536][64] ---
#define LDSIDX2(row, chunk) (((row) << 7) + ((((chunk) ^ ((row) & 7))) << 3))
__global__ __launch_bounds__(256) void gru_xgates(
    const int* __restrict__ seq, const float* __restrict__ emb,
    const float* __restrict__ w_ih, const float* __restrict__ b_ih,
    ushort_t* __restrict__ xg)
{
  __shared__ __align__(16) short lA[64 * 128];
  __shared__ __align__(16) short lB[64 * 128];
  const int tid   = threadIdx.x;
  const int sIdx  = blockIdx.x;
  const int nBase = blockIdx.y * 64;
  const int w    = tid >> 6;
  const int l    = tid & 63;
  const int l15  = l & 15;
  const int quad = l >> 4;
  floatx4 acc[4] = {};

  #pragma unroll
  for (int kp = 0; kp < 2; ++kp){
    __syncthreads();
    #pragma unroll
    for (int i = 0; i < 4; ++i){
      int lin = i * 256 + tid;
      int row = lin >> 4;
      int kc  = lin & 15;
      int kbase = kp * 128 + kc * 8;
      int token = seq[(sIdx << 6) + row];
      const float* srcA = emb  + (size_t)token * EMBD + kbase;
      const float* srcB = w_ih + (size_t)(nBase + row) * EMBD + kbase;
      floatx4 a0 = *(const floatx4*)(srcA);
      floatx4 a1 = *(const floatx4*)(srcA + 4);
      floatx4 b0 = *(const floatx4*)(srcB);
      floatx4 b1 = *(const floatx4*)(srcB + 4);
      short8 pa, pb;
      #pragma unroll
      for (int j = 0; j < 4; ++j){
        pa[j]     = (short)f2bf(a0[j]);
        pa[j + 4] = (short)f2bf(a1[j]);
        pb[j]     = (short)f2bf(b0[j]);
        pb[j + 4] = (short)f2bf(b1[j]);
      }
      *(short8*)&lA[LDSIDX2(row, kc)] = pa;
      *(short8*)&lB[LDSIDX2(row, kc)] = pb;
    }
    __syncthreads();
    #pragma unroll
    for (int kc = 0; kc < 4; ++kc){
      int chunk = kc * 4 + quad;
      short8 a = *(const short8*)&lA[LDSIDX2(w * 16 + l15, chunk)];
      #pragma unroll
      for (int s = 0; s < 4; ++s){
        short8 bf = *(const short8*)&lB[LDSIDX2(s * 16 + l15, chunk)];
        acc[s] = __builtin_amdgcn_mfma_f32_16x16x32_bf16(a, bf, acc[s], 0, 0, 0);
      }
    }
  }
  #pragma unroll
  for (int s = 0; s < 4; ++s){
    int g = nBase + s * 16 + l15;
    float bias = b_ih[g];
    ushort4v pk;
    #pragma unroll
    for (int r = 0; r < 4; ++r) pk[r] = f2bf(acc[s][r] + bias);
    *(ushort4v*)(xg + ((size_t)sIdx * G3 + g) * BATCH + (w * 16 + quad * 4)) = pk;
  }
}

// --- K2: recurrence. 256 blocks x 256 threads. ---
__global__ __launch_bounds__(256, 1) void gru_rec(
    const ushort_t* __restrict__ xg, const float* __restrict__ whh,
    const float* __restrict__ bhh, const int* __restrict__ lengths,
    char* __restrict__ truth, char* __restrict__ fastr,
    int* __restrict__ prog, int depth)
{
  __shared__ __align__(16) _Float16 wlds[48 * 64 * 8];   // 49,152 B (B-frags)
  __shared__ __align__(16) _Float16 hscr[4 * 256];       //  2,048 B (repack)
  __shared__ int s_grp, s_slc, s_fast;
  const int tid  = threadIdx.x;
  const int w    = tid >> 6;
  const int l    = tid & 63;
  const int l15  = l & 15;
  const int quad = l >> 4;
  int* flags = prog + PROGN;           // [NGRP][32] monotonic release flags

  // ---- rendezvous + XCD-affinity group formation ----
  int* regs = prog + 384;              // [0]=gcount, [1..8]=per-XCD counts
  if (tid == 0){
    unsigned xcd;
    asm volatile("s_getreg_b32 %0, hwreg(HW_REG_XCC_ID)" : "=s"(xcd));
    xcd &= 7u;
    int myx = atomicAdd(&regs[1 + xcd], 1);
    asm volatile("s_waitcnt vmcnt(0)" ::: "memory");  // xcd count visible first
    int gt = atomicAdd(&regs[0], 1);
    int v;
    do {
      asm volatile("s_sleep 1" ::: "memory");
      asm volatile("global_load_dword %0, %1, off sc0 sc1\n\t"
                   "s_waitcnt vmcnt(0)"
                   : "=v"(v) : "v"(&regs[0]) : "memory");
    } while (v < 256);
    int ok = 1;
    #pragma unroll
    for (int x = 0; x < 8; ++x){
      int c;
      asm volatile("global_load_dword %0, %1, off sc0 sc1\n\t"
                   "s_waitcnt vmcnt(0)"
                   : "=v"(c) : "v"(&regs[1 + x]) : "memory");
      ok &= (c == 32);
    }
    s_fast = ok;
    s_grp  = ok ? (int)xcd : 0;
    s_slc  = ok ? (myx & 31) : gt;
  }
  __syncthreads();
  const int fast = s_fast;
  const int grp  = s_grp;
  const int g0   = s_slc;
  if (!fast && g0 >= 32) return;       // fallback: only 32 blocks participate
  const int g = g0 & 31;               // hidden slice [g*16, g*16+16)
  const int j = g * 16 + l15;          // this lane's hidden unit

  // ---- setup: 48 W_hh rows f32->f16 into B-frag LDS (all 4 waves) ----
  #pragma unroll
  for (int i = 0; i < 12; ++i){
    int p  = i * 4 + w;                 // 0..47
    int G  = p >> 4;                    // gate (0=r,1=z,2=n)
    int ks = p & 15;                    // K-step
    const float* src = whh + (size_t)(G * HID + j) * HID + ks * 32 + quad * 8;
    floatx4 f0 = *(const floatx4*)(src);
    floatx4 f1 = *(const floatx4*)(src + 4);
    half8 hv;
    #pragma unroll
    for (int q = 0; q < 4; ++q){ hv[q] = (_Float16)f0[q]; hv[q + 4] = (_Float16)f1[q]; }
    *(half8*)&wlds[((size_t)p * 64 + l) * 8] = hv;
  }
  __syncthreads();
  if (fast && tid >= 64) return;       // fast mode: wave 0 runs alone

  char* fastb = fastr + (size_t)grp * depth * GSLOT;
  const int locb = fast ? ((quad & 1) * 4) : (quad * 4);  // wave-local batch base
  const int gb   = fast ? (grp * GRPB + locb) : (w * 16 + locb);  // global batch
  const int arow = l15 & 7;                                // fast ring A-row
  const int trow = fast ? (grp * GRPB + (l15 & 7)) : (w * 16 + l15); // truth row
  const float bhR = bhh[j], bhZ = bhh[HID + j], bhN = bhh[2 * HID + j];
  int   len[4];
  float h[4];
  #pragma unroll
  for (int r = 0; r < 4; ++r){ len[r] = lengths[gb + r]; h[r] = 0.f; }
  const int Lmax  = lengths[0];        // global max: all blocks run to Lmax
  const int mask  = depth - 1;
  const bool reuse = (depth < Lmax);
  const int flagmode = fast && !reuse; // flag-released L2 exchange
  const int* fpoll = flags + grp * 32 + (l & 31);  // this lane's polled flag
  int* fpub = flags + grp * 32 + g;                // this block's own flag
  int cmin = 0;
  int badcnt = 0;
  int fastpoll = flagmode;             // sticky downgrade switch (data path)

  for (int t = 0; t < Lmax; ++t){
    // 0) ring-reuse guard (legacy modes only; dead when depth >= Lmax)
    if (reuse && t >= depth){
      int target = t - depth + 2;
      if (cmin < target){
        int tgt2 = target + 4;
        if (fast){
          const int* pp = prog + 128 + grp * 32 + (l & 31);
          while (true){
            int p0;
            asm volatile("global_load_dword %0, %1, off sc0 sc1\n\t"
                         "s_waitcnt vmcnt(0)"
                         : "=v"(p0) : "v"(pp) : "memory");
            if (__all(p0 >= tgt2)) break;
            __builtin_amdgcn_s_sleep(2);
          }
        } else {
          while (true){
            int p0, p1;
            asm volatile("global_load_dword %0, %2, off sc0 sc1\n\t"
                         "global_load_dword %1, %3, off sc0 sc1\n\t"
                         "s_waitcnt vmcnt(0)"
                         : "=v"(p0), "=v"(p1) : "v"(prog + l), "v"(prog + 64 + l)
                         : "memory");
            if (__all(p0 >= tgt2 && p1 >= tgt2)) break;
            __builtin_amdgcn_s_sleep(2);
          }
        }
        cmin = tgt2;
      }
    }

    // 1) xg prefetch (independent of h)
    const ushort_t* xt = xg + (size_t)t * G3 * BATCH;
    ushort4v xR = __builtin_nontemporal_load(
        (const ushort4v*)(xt + (size_t)(          j) * BATCH + gb));
    ushort4v xZ = __builtin_nontemporal_load(
        (const ushort4v*)(xt + (size_t)(HID     + j) * BATCH + gb));
    ushort4v xN = __builtin_nontemporal_load(
        (const ushort4v*)(xt + (size_t)(2 * HID + j) * BATCH + gb));

    // 2) consume h(t-1)
    floatx4 aR = {0.f,0.f,0.f,0.f}, aZ = {0.f,0.f,0.f,0.f}, aN = {0.f,0.f,0.f,0.f};
    if (t > 0){
      const int slotp = (t - 1) & mask;
      const char* rowf = fastb + (size_t)slotp * GSLOT
                       + (size_t)arow * 1024 + quad * 16;
      const char* rowt = truth + (size_t)slotp * TSLOT
                       + (size_t)trow * 1024 + quad * 16;
      half8 aF[16];
      bool good = false;
      if (fastpoll){
        // 2a) flag gate: lanes 0..31 poll the 32 producers' monotonic flags
        //     (32 independent dwords -> no RMW serialization on release)
        int miss = 0;
        while (true){
          int fv;
          asm volatile("global_load_dword %0, %1, off sc0 sc1\n\t"
                       "s_waitcnt vmcnt(0)"
                       : "=v"(fv) : "v"(fpoll) : "memory");
          if (__all(fv >= t)) break;
          ++miss;
          if (miss > 64) __builtin_amdgcn_s_sleep(8);
          else           __builtin_amdgcn_s_sleep(1);
        }
        // 2b) one-shot data read from the shared XCD L2; producers' sc0
        //     stores were acked in L2 before their flag release
        #pragma unroll
        for (int ks = 0; ks < 16; ++ks){
          const char* pa = rowf + ks * 64;
          asm volatile("global_load_dwordx4 %0, %1, off sc0"
                       : "=v"(aF[ks]) : "v"(pa) : "memory");
        }
        asm volatile("s_waitcnt vmcnt(0)"
                     : "+v"(aF[0]),  "+v"(aF[1]),  "+v"(aF[2]),  "+v"(aF[3]),
                       "+v"(aF[4]),  "+v"(aF[5]),  "+v"(aF[6]),  "+v"(aF[7]),
                       "+v"(aF[8]),  "+v"(aF[9]),  "+v"(aF[10]), "+v"(aF[11]),
                       "+v"(aF[12]), "+v"(aF[13]), "+v"(aF[14]), "+v"(aF[15])
                     :: "memory");
        bool bad = false;
        #pragma unroll
        for (int ks = 0; ks < 16; ++ks) bad |= has_sent(aF[ks]);
        good = !__any(bad);
        if (!good && ++badcnt >= BAD_LIMIT) fastpoll = 0;
      }
      if (!good){
        // legacy / escalation: self-synchronizing sentinel poll on truth
        int rounds = 0;
        while (true){
          if (rounds){
            if (rounds > 64) __builtin_amdgcn_s_sleep(8);
            else             __builtin_amdgcn_s_sleep(2);
          }
          ++rounds;
          #pragma unroll
          for (int ks = 0; ks < 16; ++ks){
            const char* pa = rowt + ks * 64;
            asm volatile("global_load_dwordx4 %0, %1, off sc0 sc1"
                         : "=v"(aF[ks]) : "v"(pa) : "memory");
          }
          asm volatile("s_waitcnt vmcnt(0)"
                       : "+v"(aF[0]),  "+v"(aF[1]),  "+v"(aF[2]),  "+v"(aF[3]),
                         "+v"(aF[4]),  "+v"(aF[5]),  "+v"(aF[6]),  "+v"(aF[7]),
                         "+v"(aF[8]),  "+v"(aF[9]),  "+v"(aF[10]), "+v"(aF[11]),
                         "+v"(aF[12]), "+v"(aF[13]), "+v"(aF[14]), "+v"(aF[15])
                       :: "memory");
          bool bad = false;
          #pragma unroll
          for (int ks = 0; ks < 16; ++ks) bad |= has_sent(aF[ks]);
          if (!__any(bad)) break;
        }
      }
      #pragma unroll
      for (int ks = 0; ks < 16; ++ks){
        half8 a  = aF[ks];
        half8 b0 = *(const half8*)&wlds[((size_t)(0 * 16 + ks) * 64 + l) * 8];
        half8 b1 = *(const half8*)&wlds[((size_t)(1 * 16 + ks) * 64 + l) * 8];
        half8 b2 = *(const half8*)&wlds[((size_t)(2 * 16 + ks) * 64 + l) * 8];
        aR = __builtin_amdgcn_mfma_f32_16x16x32_f16(a, b0, aR, 0, 0, 0);
        aZ = __builtin_amdgcn_mfma_f32_16x16x32_f16(a, b1, aZ, 0, 0, 0);
        aN = __builtin_amdgcn_mfma_f32_16x16x32_f16(a, b2, aN, 0, 0, 0);
      }
      // restore sentinels on consumed truth chunks (legacy reuse only)
      if (reuse){
        uintx4 sv = {0xFFFFFFFFu, 0xFFFFFFFFu, 0xFFFFFFFFu, 0xFFFFFFFFu};
        if (!fast || l15 < 8){
          #pragma unroll
          for (int ks = 0; ks < 16; ++ks){
            const char* pt = rowt + ks * 64;
            asm volatile("global_store_dwordx4 %0, %1, off sc0 sc1"
                         :: "v"(pt), "v"(sv) : "memory");
          }
        }
      }
    }

    // 3) gates + h update (f32 carry); mirrored quads duplicate harmlessly
    #pragma unroll
    for (int r = 0; r < 4; ++r){
      float rr = sigm(bf2f(xR[r]) + aR[r] + bhR);
      float zz = sigm(bf2f(xZ[r]) + aZ[r] + bhZ);
      float nn = tanh_c(bf2f(xN[r]) + rr * (aN[r] + bhN));
      float hn = (1.f - zz) * nn + zz * h[r];
      h[r] = (t < len[r]) ? hn : h[r];
    }

    // 4) intra-wave repack via LDS, then publish h(t)
    _Float16* scr = hscr + w * 256;
    if (!fast || quad < 2){
      #pragma unroll
      for (int r = 0; r < 4; ++r) scr[(locb + r) * 16 + l15] = (_Float16)h[r];
    }
    asm volatile("s_waitcnt lgkmcnt(0)" ::: "memory");   // wave-local DS order
    if (flagmode){
      // release: fast data sc0 -> vmcnt ack -> flag store -> truth sc0 sc1
      if (l < 16){
        int bl = l >> 1;
        int hc = l & 1;
        half8 ch = *(const half8*)&scr[bl * 16 + hc * 8];
        const char* df = fastb + (size_t)(t & mask) * GSLOT
                       + (size_t)bl * 1024 + (size_t)g * 32 + (size_t)hc * 16;
        asm volatile("global_store_dwordx4 %0, %1, off sc0"
                     :: "v"(df), "v"(ch) : "memory");
      }
      asm volatile("s_waitcnt vmcnt(0)" ::: "memory");   // data in XCD L2
      if (l == 0){
        int pv = t + 1;
        asm volatile("global_store_dword %0, %1, off sc0 sc1"
                     :: "v"(fpub), "v"(pv) : "memory");
      }
      if (l < 16){
        int bl = l >> 1;
        int hc = l & 1;
        half8 ch = *(const half8*)&scr[bl * 16 + hc * 8];
        const char* dt = truth + (size_t)(t & mask) * TSLOT
                       + (size_t)(grp * GRPB + bl) * 1024
                       + (size_t)g * 32 + (size_t)hc * 16;
        asm volatile("global_store_dwordx4 %0, %1, off sc0 sc1"
                     :: "v"(dt), "v"(ch) : "memory");
      }
    } else {
      const int pubN = fast ? 16 : 32;
      if (l < pubN){
        int bl = l >> 1;
        int hc = l & 1;
        half8 ch = *(const half8*)&scr[bl * 16 + hc * 8];
        int gbatch = fast ? (grp * GRPB + bl) : (w * 16 + bl);
        const char* dt = truth + (size_t)(t & mask) * TSLOT
                       + (size_t)gbatch * 1024 + (size_t)g * 32 + (size_t)hc * 16;
        asm volatile("global_store_dwordx4 %0, %1, off sc0 sc1"
                     :: "v"(dt), "v"(ch) : "memory");
      }
      // 5) coarse progress publish (reuse mode only), ordered after restores
      if (reuse && ((t & 7) == 7)){
        asm volatile("s_waitcnt vmcnt(0)" ::: "memory");
        if (l == 0){
          int pv = t + 1;
          const int* pp = fast ? (prog + 128 + grp * 32 + g) : (prog + w * 32 + g);
          asm volatile("global_store_dword %0, %1, off sc0 sc1"
                       :: "v"(pp), "v"(pv) : "memory");
        }
      }
    }
  }
}

// --- K3: logits + log_softmax from truth slot (Lmax-1). 64 blocks x 64. ---
__global__ __launch_bounds__(64) void gru_out(
    const char* __restrict__ truth, const int* __restrict__ lengths,
    const float* __restrict__ wout, const float* __restrict__ bout,
    float* __restrict__ out, int depth)
{
  const int b = blockIdx.x, l = threadIdx.x;
  const int Lmax = lengths[0];
  const _Float16* h = (const _Float16*)(truth
      + (size_t)((Lmax - 1) & (depth - 1)) * TSLOT + (size_t)b * 1024);
  half8 hv = *(const half8*)(h + l * 8);
  float p[NOUT];
  #pragma unroll
  for (int o = 0; o < NOUT; ++o){
    const float* wr = wout + o * HID + l * 8;
    float a = 0.f;
    #pragma unroll
    for (int i = 0; i < 8; ++i) a += wr[i] * (float)hv[i];
    #pragma unroll
    for (int d = 32; d >= 1; d >>= 1) a += __shfl_down(a, d, 64);
    p[o] = a;
  }
  if (l == 0){
    float lg[NOUT], m = -1e30f;
    #pragma unroll
    for (int o = 0; o < NOUT; ++o){
      float v = p[o] + bout[o];
      if (!(v == v)) v = -1.0f;
      lg[o] = v; m = fmaxf(m, v);
    }
    float ssum = 0.f;
    #pragma unroll
    for (int o = 0; o < NOUT; ++o) ssum += __expf(lg[o] - m);
    float ls = __logf(ssum);
    #pragma unroll
    for (int o = 0; o < NOUT; ++o) out[b * NOUT + o] = lg[o] - m - ls;
  }
}

extern "C" void kernel_launch(void* const* d_in, const int* in_sizes, int n_in,
                              void* d_out, int out_size, void* d_ws, size_t ws_size,
                              hipStream_t stream) {
  (void)in_sizes; (void)n_in; (void)out_size;
  const int*   seq     = (const int*)d_in[0];
  const int*   lengths = (const int*)d_in[1];
  const float* emb     = (const float*)d_in[2];
  const float* w_ih    = (const float*)d_in[3];
  const float* w_hh    = (const float*)d_in[4];
  const float* b_ih    = (const float*)d_in[5];
  const float* b_hh    = (const float*)d_in[6];
  const float* w_out   = (const float*)d_in[7];
  const float* b_out   = (const float*)d_in[8];
  float*       outp    = (float*)d_out;

  // ring depth: largest power of two in [16, 512] such that both rings
  // (depth * 128 KiB) + prog/flags fit the workspace after xg.
  size_t avail = (ws_size > (size_t)XG_BYTES + 32768)
               ? ws_size - (size_t)XG_BYTES - 32768 : 0;
  int depth = 16;
  while (depth < 512 && ((size_t)(depth << 1) * RING2) <= avail) depth <<= 1;

  char* ws = (char*)d_ws;
  ushort_t* xg    = (ushort_t*)ws;                                 // 100,663,296 B
  char*     truth = ws + XG_BYTES;                                 // depth*65,536 B
  char*     fastr = truth + (size_t)depth * TSLOT;                 // depth*65,536 B
  int*      prog  = (int*)(fastr + (size_t)depth * TSLOT);         // 768 ints

  gru_init<<<depth * 32, 256, 0, stream>>>(truth, prog);
  dim3 g1(SEQL, G3 / 64);
  gru_xgates<<<g1, 256, 0, stream>>>(seq, emb, w_ih, b_ih, xg);
  gru_rec<<<256, 256, 0, stream>>>(xg, w_hh, b_hh, lengths, truth, fastr, prog, depth);
  gru_out<<<BATCH, 64, 0, stream>>>(truth, lengths, w_out, b_out, outp, depth);
}